// Round 11
// baseline (104.902 us; speedup 1.0000x reference)
//
#include <hip/hip_runtime.h>

typedef unsigned short u16;
typedef short bf16x8 __attribute__((ext_vector_type(8)));
typedef float f32x4 __attribute__((ext_vector_type(4)));
typedef float f32x16 __attribute__((ext_vector_type(16)));

#define BATCH 2
#define SEQ   2048
#define CH    1024
#define NHEAD 16
#define HDIM  64
#define ROWS  (BATCH*SEQ)   // 4096

#define WAITV(N) asm volatile("s_waitcnt vmcnt(" #N ")" ::: "memory")

__device__ __forceinline__ u16 f2b(float f) {
  unsigned u = __builtin_bit_cast(unsigned, f);
  u += 0x7FFFu + ((u >> 16) & 1u);
  return (u16)(u >> 16);
}
__device__ __forceinline__ float b2f(u16 h) {
  unsigned u = ((unsigned)h) << 16;
  return __builtin_bit_cast(float, u);
}
__device__ __forceinline__ float exp2_fast(float x) {
  float r; asm("v_exp_f32 %0, %1" : "=v"(r) : "v"(x)); return r;
}
__device__ __forceinline__ unsigned cvt_pk_bf16(float a, float b) {
  unsigned r; asm("v_cvt_pk_bf16_f32 %0, %1, %2" : "=v"(r) : "v"(a), "v"(b)); return r;
}

__device__ __forceinline__ void gload_lds16(const void* g, void* l) {
  __builtin_amdgcn_global_load_lds(
      (const __attribute__((address_space(1))) unsigned int*)g,
      (__attribute__((address_space(3))) unsigned int*)l, 16, 0, 0);
}

// ---------- fused prep: x f32->bf16, both weight transposes (one launch) ----
__global__ void csa_prep(const float* __restrict__ x,
                         const float* __restrict__ wa, const float* __restrict__ wp,
                         u16* __restrict__ xb, u16* __restrict__ wat,
                         u16* __restrict__ wpt) {
  __shared__ float tile[32][33];
  const int b = blockIdx.x, t = threadIdx.x;
  if (b < 2048) {               // convert x: 524288 uint4-pairs
    int i = b * 256 + t;
    const float4* f4 = (const float4*)x;
    float4 v0 = f4[2*i], v1 = f4[2*i+1];
    ushort4 o0, o1;
    o0.x = f2b(v0.x); o0.y = f2b(v0.y); o0.z = f2b(v0.z); o0.w = f2b(v0.w);
    o1.x = f2b(v1.x); o1.y = f2b(v1.y); o1.z = f2b(v1.z); o1.w = f2b(v1.w);
    ((ushort4*)xb)[2*i]   = o0;
    ((ushort4*)xb)[2*i+1] = o1;
    return;
  }
  int bb = b - 2048;            // transpose: 4096 blocks (128 x 32)
  int bx = bb & 127, by = bb >> 7;
  const float* in; u16* out; int C;
  if (bx < 96) { in = wa; out = wat; C = 3*CH; }
  else         { in = wp; out = wpt; C = CH; bx -= 96; }
  const int R = CH;
  const int bxc = bx * 32, byc = by * 32;
  const int tx = t & 31, ty = t >> 5;
  #pragma unroll
  for (int j = 0; j < 4; ++j) {
    int r = byc + ty + j*8, c = bxc + tx;
    tile[ty + j*8][tx] = in[(size_t)r*C + c];
  }
  __syncthreads();
  #pragma unroll
  for (int j = 0; j < 4; ++j) {
    int oc = bxc + ty + j*8;
    int orr = byc + tx;
    out[(size_t)oc*R + orr] = f2b(tile[tx][ty + j*8]);
  }
}

// ---------- QKV GEMM: [4096][3072] = xb * wat^T + b (unchanged from R9) -----
__global__ __launch_bounds__(512) void csa_gemm_qkv(
    const u16* __restrict__ A, const u16* __restrict__ Bt,
    const float* __restrict__ bias,
    u16* __restrict__ qbo, u16* __restrict__ kb, u16* __restrict__ vtb)
{
  __shared__ __align__(16) u16 As[3][256*64];   // 96 KB
  __shared__ __align__(16) u16 Bs[2][192*64];   // 48 KB
  const int t = threadIdx.x, lane = t & 63, w = t >> 6;
  const int wm = w >> 2, wn = w & 3, g = lane >> 4, qi = lane & 15;
  const int xq = (qi & 7) * 8;

  const int wgid = blockIdx.y * 16 + blockIdx.x;
  const int c8 = wgid & 7, inner = wgid >> 3;
  const int bm = (c8 >> 1) * 4 + (inner >> 3);
  const int bn = (c8 & 1) * 8 + (inner & 7);

  f32x4 acc[8][3] = {};

  const u16* Ab = A  + (size_t)(bm*256)*CH;
  const u16* Bb = Bt + (size_t)(bn*192)*CH;
  const int srow = t >> 3;                               // 0..63
  const int scolsw = ((t & 7) * 8) ^ ((srow & 7) * 8);   // pre-swizzled src col

#define QKV_STAGE_A(kt_, buf_) do { const size_t k_ = (size_t)(kt_)*64;            \
    gload_lds16(Ab + (size_t)(  0 + srow)*CH + k_ + scolsw, &As[buf_][      w*512]); \
    gload_lds16(Ab + (size_t)( 64 + srow)*CH + k_ + scolsw, &As[buf_][ 4096+w*512]); \
    gload_lds16(Ab + (size_t)(128 + srow)*CH + k_ + scolsw, &As[buf_][ 8192+w*512]); \
    gload_lds16(Ab + (size_t)(192 + srow)*CH + k_ + scolsw, &As[buf_][12288+w*512]); \
  } while (0)
#define QKV_STAGE_B(kt_, buf_) do { const size_t k_ = (size_t)(kt_)*64;            \
    gload_lds16(Bb + (size_t)(  0 + srow)*CH + k_ + scolsw, &Bs[buf_][      w*512]); \
    gload_lds16(Bb + (size_t)( 64 + srow)*CH + k_ + scolsw, &Bs[buf_][ 4096+w*512]); \
    gload_lds16(Bb + (size_t)(128 + srow)*CH + k_ + scolsw, &Bs[buf_][ 8192+w*512]); \
  } while (0)

  QKV_STAGE_A(0, 0); QKV_STAGE_B(0, 0); QKV_STAGE_A(1, 1);

  int a3 = 0;
  for (int kt = 0; kt < 16; ++kt) {
    if (kt < 15) QKV_STAGE_B(kt + 1, (kt + 1) & 1);
    if (kt < 14) { int ab = a3 + 2; if (ab >= 3) ab -= 3; QKV_STAGE_A(kt + 2, ab); }
    if (kt < 14)       WAITV(11);
    else if (kt == 14) WAITV(7);
    else               WAITV(0);
    __builtin_amdgcn_s_barrier();
    __builtin_amdgcn_sched_barrier(0);
    const u16* Ac = &As[a3][0];
    const u16* Bc = &Bs[kt & 1][0];
    #pragma unroll
    for (int kk = 0; kk < 2; ++kk) {
      bf16x8 af[8], bfr[3];
      #pragma unroll
      for (int m = 0; m < 8; ++m)
        af[m] = *(const bf16x8*)&Ac[(wm*128 + m*16 + qi)*64 + ((kk*32 + g*8) ^ xq)];
      #pragma unroll
      for (int n = 0; n < 3; ++n)
        bfr[n] = *(const bf16x8*)&Bc[(wn*48 + n*16 + qi)*64 + ((kk*32 + g*8) ^ xq)];
      #pragma unroll
      for (int m = 0; m < 8; ++m)
        #pragma unroll
        for (int n = 0; n < 3; ++n)
          acc[m][n] = __builtin_amdgcn_mfma_f32_16x16x32_bf16(af[m], bfr[n], acc[m][n], 0, 0, 0);
    }
    __builtin_amdgcn_s_barrier();
    a3 = (a3 == 2) ? 0 : a3 + 1;
  }
#undef QKV_STAGE_A
#undef QKV_STAGE_B

  #pragma unroll
  for (int m = 0; m < 8; ++m) {
    const int row0 = bm*256 + wm*128 + m*16 + g*4;
    const int bb = row0 >> 11;
    const int t0 = row0 & 2047;
    #pragma unroll
    for (int n = 0; n < 3; ++n) {
      const int col = bn*192 + wn*48 + n*16 + qi;
      const float bv = bias[col];
      const int which = col >> 10;      // 0=q 1=k 2=v
      const int cc = col & 1023;
      const int h = cc >> 6, d = cc & 63;
      const int bh = bb*16 + h;
      if (which == 2) {
        ushort4 pw;
        pw.x = f2b(acc[m][n][0] + bv);
        pw.y = f2b(acc[m][n][1] + bv);
        pw.z = f2b(acc[m][n][2] + bv);
        pw.w = f2b(acc[m][n][3] + bv);
        *(ushort4*)&vtb[((size_t)bh*HDIM + d)*SEQ + t0] = pw;
      } else {
        u16* dst = (which == 0) ? qbo : kb;
        #pragma unroll
        for (int r = 0; r < 4; ++r)
          dst[((size_t)bh*SEQ + t0 + r)*HDIM + d] = f2b(acc[m][n][r] + bv);
      }
    }
  }
}

// ---------- proj GEMM: out[4096][1024] f32 = y * wpt^T + b (unchanged R9) ---
__global__ __launch_bounds__(256) void csa_gemm_proj(
    const u16* __restrict__ A, const u16* __restrict__ Bt,
    const float* __restrict__ bias, float* __restrict__ out)
{
  __shared__ __align__(16) u16 As[3][128*64];   // 48 KB
  __shared__ __align__(16) u16 Bs[2][128*64];   // 32 KB
  const int t = threadIdx.x, lane = t & 63, w = t >> 6;
  const int wm = w >> 1, wn = w & 1, g = lane >> 4, qi = lane & 15;
  const int xq = (qi & 7) * 8;
  const int bm = blockIdx.y, bn = blockIdx.x;

  f32x4 acc[4][4] = {};

  const u16* Ab = A  + (size_t)(bm*128)*CH;
  const u16* Bb = Bt + (size_t)(bn*128)*CH;
  const int srow = t >> 3;                               // 0..31
  const int scolsw = ((t & 7) * 8) ^ ((srow & 7) * 8);

#define PRJ_STAGE(P_, base_, kt_, buf_) do { const size_t k_ = (size_t)(kt_)*64;      \
    gload_lds16(P_ + (size_t)( 0 + srow)*CH + k_ + scolsw, &base_[buf_][     w*512]); \
    gload_lds16(P_ + (size_t)(32 + srow)*CH + k_ + scolsw, &base_[buf_][2048+w*512]); \
    gload_lds16(P_ + (size_t)(64 + srow)*CH + k_ + scolsw, &base_[buf_][4096+w*512]); \
    gload_lds16(P_ + (size_t)(96 + srow)*CH + k_ + scolsw, &base_[buf_][6144+w*512]); \
  } while (0)

  PRJ_STAGE(Ab, As, 0, 0); PRJ_STAGE(Bb, Bs, 0, 0); PRJ_STAGE(Ab, As, 1, 1);

  int a3 = 0;
  for (int kt = 0; kt < 16; ++kt) {
    if (kt < 15) PRJ_STAGE(Bb, Bs, kt + 1, (kt + 1) & 1);
    if (kt < 14) { int ab = a3 + 2; if (ab >= 3) ab -= 3; PRJ_STAGE(Ab, As, kt + 2, ab); }
    if (kt < 14)       WAITV(12);
    else if (kt == 14) WAITV(8);
    else               WAITV(0);
    __builtin_amdgcn_s_barrier();
    __builtin_amdgcn_sched_barrier(0);
    const u16* Ac = &As[a3][0];
    const u16* Bc = &Bs[kt & 1][0];
    #pragma unroll
    for (int kk = 0; kk < 2; ++kk) {
      bf16x8 af[4], bfr[4];
      #pragma unroll
      for (int m = 0; m < 4; ++m)
        af[m] = *(const bf16x8*)&Ac[(wm*64 + m*16 + qi)*64 + ((kk*32 + g*8) ^ xq)];
      #pragma unroll
      for (int n = 0; n < 4; ++n)
        bfr[n] = *(const bf16x8*)&Bc[(wn*64 + n*16 + qi)*64 + ((kk*32 + g*8) ^ xq)];
      #pragma unroll
      for (int m = 0; m < 4; ++m)
        #pragma unroll
        for (int n = 0; n < 4; ++n)
          acc[m][n] = __builtin_amdgcn_mfma_f32_16x16x32_bf16(af[m], bfr[n], acc[m][n], 0, 0, 0);
    }
    __builtin_amdgcn_s_barrier();
    a3 = (a3 == 2) ? 0 : a3 + 1;
  }
#undef PRJ_STAGE

  #pragma unroll
  for (int m = 0; m < 4; ++m) {
    const int row0 = bm*128 + wm*64 + m*16 + g*4;
    #pragma unroll
    for (int n = 0; n < 4; ++n) {
      const int col = bn*128 + wn*64 + n*16 + qi;
      const float bv = bias[col];
      #pragma unroll
      for (int r = 0; r < 4; ++r)
        out[(size_t)(row0 + r)*CH + col] = acc[m][n][r] + bv;
    }
  }
}

// ---------- causal flash attention v7: 32x32 MFMA + in-register P (T12) -----
// grid 32 x 8, 512 thr = 8 waves. Wave = (j = q-subtile 0..3 of 32 rows,
// sub = key-half 0/1). q-tile 128 rows, KVBLK=128 (each wave computes its
// 64-key half); pairs {p, 15-p} -> uniform 17 iterations. Swapped QK^T with
// mfma_f32_32x32x16 (D[key][q]: col=lane&31=q, row=(reg&3)+8(reg>>2)+4hi).
// P stays IN REGISTER: 16 cvt_pk + 8 permlane32_swap reformat P into PV's
// A-operand fragments (keys ks*16+hi*8+e). Wave pairs keep independent
// online-softmax states over disjoint key halves; flash-combine at epilogue
// via LDS (Ocomb aliases Ks). K row-XOR swizzle; V slot-swizzle (^d&15).
__global__ __launch_bounds__(512) void csa_attn(
    const u16* __restrict__ qb, const u16* __restrict__ kb,
    const u16* __restrict__ vtb, u16* __restrict__ yout)
{
  const int bh = blockIdx.x, pair = blockIdx.y;
  const int bidx = bh >> 4, h = bh & 15;
  const int t = threadIdx.x, lane = t & 63, w = t >> 6;   // w 0..7
  const int j = w >> 1, sub = w & 1;
  const int l31 = lane & 31, hi = lane >> 5;

  __shared__ __align__(16) u16 Ks[2][128*64];   // 32 KB [key][d] swizzled
  __shared__ __align__(16) u16 Vs[2][64*128];   // 32 KB [d][key] slot-swizzled
  __shared__ float mtab[8][32], stab[8][32], ftab[8][32];

  const size_t kvbase = (size_t)bh * SEQ * HDIM;
  const u16* kb_bh  = kb  + kvbase;
  const u16* vtb_bh = vtb + kvbase;

  // staging geometry (512 thr): K rows t>>3, V d-rows t>>4; inverse-swizzled src
  const int krow = t >> 3;                        // 0..63
  const int kcol = 8 * ((t & 7) ^ (krow & 7));
  const int vrow = t >> 4;                        // 0..31
  const int vcol = 8 * ((t & 15) ^ (vrow & 15));

#define ATTN_STAGE(kt_, b_) do {                                             \
    const u16* kp_ = kb_bh + (size_t)((kt_)*128 + krow)*64 + kcol;           \
    gload_lds16(kp_,           &Ks[b_][       w*512]);                       \
    gload_lds16(kp_ + 64*64,   &Ks[b_][4096 + w*512]);                       \
    const u16* vp_ = vtb_bh + (size_t)vrow*SEQ + (kt_)*128 + vcol;           \
    gload_lds16(vp_,           &Vs[b_][       w*512]);                       \
    gload_lds16(vp_ + 32*SEQ,  &Vs[b_][4096 + w*512]);                       \
  } while (0)

  // K A-fragment offsets [kb][ds]: row = sub*64+kb*32+l31, d = ds*16+hi*8
  int offK[2][4];
  #pragma unroll
  for (int kb2 = 0; kb2 < 2; ++kb2)
    #pragma unroll
    for (int ds = 0; ds < 4; ++ds)
      offK[kb2][ds] = (sub*64 + kb2*32 + l31)*64 + ((ds*16 + hi*8) ^ ((l31 & 7)*8));
  // V B-fragment offsets [db][ks]: d = db*32+l31, key = sub*64+ks*16+hi*8
  int offV[2][4];
  #pragma unroll
  for (int db = 0; db < 2; ++db)
    #pragma unroll
    for (int ks = 0; ks < 4; ++ks)
      offV[db][ks] = (db*32 + l31)*128 + (((sub*8 + 2*ks + hi) ^ (l31 & 15))*8);

#define PACK(ps_, b_, out_) do {                                             \
    unsigned A0_ = cvt_pk_bf16(ps_[(b_)+0], ps_[(b_)+1]);                    \
    unsigned A1_ = cvt_pk_bf16(ps_[(b_)+2], ps_[(b_)+3]);                    \
    unsigned B0_ = cvt_pk_bf16(ps_[(b_)+4], ps_[(b_)+5]);                    \
    unsigned B1_ = cvt_pk_bf16(ps_[(b_)+6], ps_[(b_)+7]);                    \
    asm volatile("v_permlane32_swap_b32 %0, %1" : "+v"(A0_), "+v"(B0_));     \
    asm volatile("v_permlane32_swap_b32 %0, %1" : "+v"(A1_), "+v"(B1_));     \
    union { unsigned u[4]; bf16x8 v; } pu_;                                  \
    pu_.u[0] = A0_; pu_.u[1] = A1_; pu_.u[2] = B0_; pu_.u[3] = B1_;          \
    out_ = pu_.v;                                                            \
  } while (0)

  const float QSCALE = 0.18033688011112042f;   // 0.125 * log2(e)
  const int qloc = j*32 + l31;

  for (int half = 0; half < 2; ++half) {
    const int qt = half ? (15 - pair) : pair;
    const int ntile = qt + 1;
    const int qrow = qt*128 + j*32;

    // Q B-operand: col=lane&31=q, k=(lane>>5)*8+e; pre-scaled (exp2 domain)
    bf16x8 qf[4];
    #pragma unroll
    for (int ds = 0; ds < 4; ++ds) {
      qf[ds] = *(const bf16x8*)&qb[kvbase + (size_t)(qrow + l31)*HDIM + ds*16 + hi*8];
      #pragma unroll
      for (int e = 0; e < 8; ++e)
        qf[ds][e] = (short)f2b(b2f((u16)qf[ds][e]) * QSCALE);
    }

    f32x16 yacc0 = {}, yacc1 = {};        // O[d-block 0/1]: row=q=crow, col=d
    float mrun = -1e30f, srun = 0.f;      // per-lane (q = l31), pair-synced m

    ATTN_STAGE(0, 0);
    __syncthreads();

    int buf = 0;
    for (int kt = 0; kt < ntile; ++kt) {
      if (kt + 1 < ntile) ATTN_STAGE(kt + 1, buf ^ 1);

      // S^T = K * Q^T (two 32-key blocks of this wave's 64-key half)
      f32x16 s0 = {}, s1 = {};
      #pragma unroll
      for (int ds = 0; ds < 4; ++ds) {
        bf16x8 k0 = *(const bf16x8*)&Ks[buf][offK[0][ds]];
        s0 = __builtin_amdgcn_mfma_f32_32x32x16_bf16(k0, qf[ds], s0, 0, 0, 0);
        bf16x8 k1 = *(const bf16x8*)&Ks[buf][offK[1][ds]];
        s1 = __builtin_amdgcn_mfma_f32_32x32x16_bf16(k1, qf[ds], s1, 0, 0, 0);
      }

      // causal mask on the diagonal 128-key tile
      if (kt == ntile - 1) {
        #pragma unroll
        for (int reg = 0; reg < 16; ++reg) {
          const int cr = (reg & 3) + 8*(reg >> 2) + 4*hi;
          if (sub*64 + cr > qloc)      s0[reg] = -3.0e38f;
          if (sub*64 + 32 + cr > qloc) s1[reg] = -3.0e38f;
        }
      }

      // online softmax (exp2 domain), defer-max; m pair-synced, s per-lane
      float tmax = fmaxf(s0[0], s1[0]);
      #pragma unroll
      for (int reg = 1; reg < 16; ++reg)
        tmax = fmaxf(tmax, fmaxf(s0[reg], s1[reg]));
      if (!__all(tmax - mrun <= 11.5f)) {       // rare true rescale
        float tmf = fmaxf(tmax, __shfl_xor(tmax, 32));
        float mnew = fmaxf(mrun, tmf);
        float fac = exp2_fast(mrun - mnew);
        if (lane < 32) ftab[w][l31] = fac;      // q-indexed -> crow-indexed
        #pragma unroll
        for (int reg = 0; reg < 16; ++reg) {
          float fr = ftab[w][(reg & 3) + 8*(reg >> 2) + 4*hi];
          yacc0[reg] *= fr; yacc1[reg] *= fr;
        }
        srun *= fac; mrun = mnew;
      }
      float tsum = 0.f;
      #pragma unroll
      for (int reg = 0; reg < 16; ++reg) {
        float p0 = exp2_fast(s0[reg] - mrun);
        float p1 = exp2_fast(s1[reg] - mrun);
        s0[reg] = p0; s1[reg] = p1;
        tsum += p0 + p1;
      }
      srun += tsum;

      // T12: in-register P -> PV A-fragments (keys ks*16 + hi*8 + e)
      bf16x8 pa0, pa1, pa2, pa3;
      PACK(s0, 0, pa0); PACK(s0, 8, pa1); PACK(s1, 0, pa2); PACK(s1, 8, pa3);

      // O += P * V
      yacc0 = __builtin_amdgcn_mfma_f32_32x32x16_bf16(pa0, *(const bf16x8*)&Vs[buf][offV[0][0]], yacc0, 0, 0, 0);
      yacc0 = __builtin_amdgcn_mfma_f32_32x32x16_bf16(pa1, *(const bf16x8*)&Vs[buf][offV[0][1]], yacc0, 0, 0, 0);
      yacc0 = __builtin_amdgcn_mfma_f32_32x32x16_bf16(pa2, *(const bf16x8*)&Vs[buf][offV[0][2]], yacc0, 0, 0, 0);
      yacc0 = __builtin_amdgcn_mfma_f32_32x32x16_bf16(pa3, *(const bf16x8*)&Vs[buf][offV[0][3]], yacc0, 0, 0, 0);
      yacc1 = __builtin_amdgcn_mfma_f32_32x32x16_bf16(pa0, *(const bf16x8*)&Vs[buf][offV[1][0]], yacc1, 0, 0, 0);
      yacc1 = __builtin_amdgcn_mfma_f32_32x32x16_bf16(pa1, *(const bf16x8*)&Vs[buf][offV[1][1]], yacc1, 0, 0, 0);
      yacc1 = __builtin_amdgcn_mfma_f32_32x32x16_bf16(pa2, *(const bf16x8*)&Vs[buf][offV[1][2]], yacc1, 0, 0, 0);
      yacc1 = __builtin_amdgcn_mfma_f32_32x32x16_bf16(pa3, *(const bf16x8*)&Vs[buf][offV[1][3]], yacc1, 0, 0, 0);

      __syncthreads();
      buf ^= 1;
    }

    // epilogue: flash-combine the wave pair (sub 0 + sub 1)
    float sfull = srun + __shfl_xor(srun, 32);
    if (lane < 32) { mtab[w][l31] = mrun; stab[w][l31] = sfull; }
    __syncthreads();

    float* Ocomb = (float*)&Ks[0][0];     // [4][32 q][64 d] f32 = 32 KB
    const int wA = w & ~1, wB = w | 1;
    if (sub == 1) {
      #pragma unroll
      for (int reg = 0; reg < 16; ++reg) {
        const int cr = (reg & 3) + 8*(reg >> 2) + 4*hi;
        float mA = mtab[wA][cr], mB = mtab[wB][cr];
        float fB = exp2_fast(mB - fmaxf(mA, mB));
        Ocomb[(j*32 + cr)*64 +      l31] = yacc0[reg] * fB;
        Ocomb[(j*32 + cr)*64 + 32 + l31] = yacc1[reg] * fB;
      }
    }
    __syncthreads();
    if (sub == 0) {
      #pragma unroll
      for (int reg = 0; reg < 16; ++reg) {
        const int cr = (reg & 3) + 8*(reg >> 2) + 4*hi;
        float mA = mtab[wA][cr], mB = mtab[wB][cr];
        float sA = stab[wA][cr], sB = stab[wB][cr];
        float ms = fmaxf(mA, mB);
        float fA = exp2_fast(mA - ms), fB = exp2_fast(mB - ms);
        float inv = 1.f / (sA * fA + sB * fB);
        const size_t orow = ((size_t)bidx*SEQ + qt*128 + j*32 + cr)*CH + h*HDIM;
        float v0 = (yacc0[reg] * fA + Ocomb[(j*32 + cr)*64 +      l31]) * inv;
        float v1 = (yacc1[reg] * fA + Ocomb[(j*32 + cr)*64 + 32 + l31]) * inv;
        yout[orow +      l31] = f2b(v0);
        yout[orow + 32 + l31] = f2b(v1);
      }
    }
    __syncthreads();   // Ocomb aliases Ks: done before next half restages
  }
#undef ATTN_STAGE
#undef PACK
}

extern "C" void kernel_launch(void* const* d_in, const int* in_sizes, int n_in,
                              void* d_out, int out_size, void* d_ws, size_t ws_size,
                              hipStream_t stream) {
  (void)in_sizes; (void)n_in; (void)out_size; (void)ws_size;
  const float* x      = (const float*)d_in[0];
  const float* w_attn = (const float*)d_in[1];
  const float* b_attn = (const float*)d_in[2];
  const float* w_proj = (const float*)d_in[3];
  const float* b_proj = (const float*)d_in[4];

  char* ws = (char*)d_ws;
  const size_t MB = 1024*1024;
  u16* xb  = (u16*)(ws);             // 8 MB, reused as attention out y
  u16* wat = (u16*)(ws +  8*MB);     // 6 MB  w_attn^T [3072][1024]
  u16* wpt = (u16*)(ws + 14*MB);     // 2 MB  w_proj^T [1024][1024]
  u16* qb  = (u16*)(ws + 16*MB);     // 8 MB  [bh][t][64]
  u16* kb  = (u16*)(ws + 24*MB);     // 8 MB  [bh][t][64]
  u16* vtb = (u16*)(ws + 32*MB);     // 8 MB  [bh][64][t]

  csa_prep<<<6144, 256, 0, stream>>>(x, w_attn, w_proj, xb, wat, wpt);
  csa_gemm_qkv<<<dim3(16, 16), 512, 0, stream>>>(xb, wat, b_attn, qb, kb, vtb);
  csa_attn<<<dim3(32, 8), 512, 0, stream>>>(qb, kb, vtb, xb);
  csa_gemm_proj<<<dim3(8, 32), 256, 0, stream>>>(xb, wpt, b_proj, (float*)d_out);
}

// Round 12
// 102.772 us; speedup vs baseline: 1.0207x; 1.0207x over previous
//
#include <hip/hip_runtime.h>

typedef unsigned short u16;
typedef short bf16x8 __attribute__((ext_vector_type(8)));
typedef float f32x4 __attribute__((ext_vector_type(4)));
typedef float f32x16 __attribute__((ext_vector_type(16)));

#define BATCH 2
#define SEQ   2048
#define CH    1024
#define NHEAD 16
#define HDIM  64
#define ROWS  (BATCH*SEQ)   // 4096

#define WAITV(N) asm volatile("s_waitcnt vmcnt(" #N ")" ::: "memory")

__device__ __forceinline__ u16 f2b(float f) {
  unsigned u = __builtin_bit_cast(unsigned, f);
  u += 0x7FFFu + ((u >> 16) & 1u);
  return (u16)(u >> 16);
}
__device__ __forceinline__ float b2f(u16 h) {
  unsigned u = ((unsigned)h) << 16;
  return __builtin_bit_cast(float, u);
}
__device__ __forceinline__ float exp2_fast(float x) {
  float r; asm("v_exp_f32 %0, %1" : "=v"(r) : "v"(x)); return r;
}
__device__ __forceinline__ unsigned cvt_pk_bf16(float a, float b) {
  unsigned r; asm("v_cvt_pk_bf16_f32 %0, %1, %2" : "=v"(r) : "v"(a), "v"(b)); return r;
}

__device__ __forceinline__ void gload_lds16(const void* g, void* l) {
  __builtin_amdgcn_global_load_lds(
      (const __attribute__((address_space(1))) unsigned int*)g,
      (__attribute__((address_space(3))) unsigned int*)l, 16, 0, 0);
}

// ---------- fused prep: x f32->bf16, both weight transposes (one launch) ----
__global__ void csa_prep(const float* __restrict__ x,
                         const float* __restrict__ wa, const float* __restrict__ wp,
                         u16* __restrict__ xb, u16* __restrict__ wat,
                         u16* __restrict__ wpt) {
  __shared__ float tile[32][33];
  const int b = blockIdx.x, t = threadIdx.x;
  if (b < 2048) {               // convert x: 524288 uint4-pairs
    int i = b * 256 + t;
    const float4* f4 = (const float4*)x;
    float4 v0 = f4[2*i], v1 = f4[2*i+1];
    ushort4 o0, o1;
    o0.x = f2b(v0.x); o0.y = f2b(v0.y); o0.z = f2b(v0.z); o0.w = f2b(v0.w);
    o1.x = f2b(v1.x); o1.y = f2b(v1.y); o1.z = f2b(v1.z); o1.w = f2b(v1.w);
    ((ushort4*)xb)[2*i]   = o0;
    ((ushort4*)xb)[2*i+1] = o1;
    return;
  }
  int bb = b - 2048;            // transpose: 4096 blocks (128 x 32)
  int bx = bb & 127, by = bb >> 7;
  const float* in; u16* out; int C;
  if (bx < 96) { in = wa; out = wat; C = 3*CH; }
  else         { in = wp; out = wpt; C = CH; bx -= 96; }
  const int R = CH;
  const int bxc = bx * 32, byc = by * 32;
  const int tx = t & 31, ty = t >> 5;
  #pragma unroll
  for (int j = 0; j < 4; ++j) {
    int r = byc + ty + j*8, c = bxc + tx;
    tile[ty + j*8][tx] = in[(size_t)r*C + c];
  }
  __syncthreads();
  #pragma unroll
  for (int j = 0; j < 4; ++j) {
    int oc = bxc + ty + j*8;
    int orr = byc + tx;
    out[(size_t)oc*R + orr] = f2b(tile[tx][ty + j*8]);
  }
}

// ---------- QKV GEMM: [4096][3072] = xb * wat^T + b (unchanged from R9) -----
__global__ __launch_bounds__(512) void csa_gemm_qkv(
    const u16* __restrict__ A, const u16* __restrict__ Bt,
    const float* __restrict__ bias,
    u16* __restrict__ qbo, u16* __restrict__ kb, u16* __restrict__ vtb)
{
  __shared__ __align__(16) u16 As[3][256*64];   // 96 KB
  __shared__ __align__(16) u16 Bs[2][192*64];   // 48 KB
  const int t = threadIdx.x, lane = t & 63, w = t >> 6;
  const int wm = w >> 2, wn = w & 3, g = lane >> 4, qi = lane & 15;
  const int xq = (qi & 7) * 8;

  const int wgid = blockIdx.y * 16 + blockIdx.x;
  const int c8 = wgid & 7, inner = wgid >> 3;
  const int bm = (c8 >> 1) * 4 + (inner >> 3);
  const int bn = (c8 & 1) * 8 + (inner & 7);

  f32x4 acc[8][3] = {};

  const u16* Ab = A  + (size_t)(bm*256)*CH;
  const u16* Bb = Bt + (size_t)(bn*192)*CH;
  const int srow = t >> 3;                               // 0..63
  const int scolsw = ((t & 7) * 8) ^ ((srow & 7) * 8);   // pre-swizzled src col

#define QKV_STAGE_A(kt_, buf_) do { const size_t k_ = (size_t)(kt_)*64;            \
    gload_lds16(Ab + (size_t)(  0 + srow)*CH + k_ + scolsw, &As[buf_][      w*512]); \
    gload_lds16(Ab + (size_t)( 64 + srow)*CH + k_ + scolsw, &As[buf_][ 4096+w*512]); \
    gload_lds16(Ab + (size_t)(128 + srow)*CH + k_ + scolsw, &As[buf_][ 8192+w*512]); \
    gload_lds16(Ab + (size_t)(192 + srow)*CH + k_ + scolsw, &As[buf_][12288+w*512]); \
  } while (0)
#define QKV_STAGE_B(kt_, buf_) do { const size_t k_ = (size_t)(kt_)*64;            \
    gload_lds16(Bb + (size_t)(  0 + srow)*CH + k_ + scolsw, &Bs[buf_][      w*512]); \
    gload_lds16(Bb + (size_t)( 64 + srow)*CH + k_ + scolsw, &Bs[buf_][ 4096+w*512]); \
    gload_lds16(Bb + (size_t)(128 + srow)*CH + k_ + scolsw, &Bs[buf_][ 8192+w*512]); \
  } while (0)

  QKV_STAGE_A(0, 0); QKV_STAGE_B(0, 0); QKV_STAGE_A(1, 1);

  int a3 = 0;
  for (int kt = 0; kt < 16; ++kt) {
    if (kt < 15) QKV_STAGE_B(kt + 1, (kt + 1) & 1);
    if (kt < 14) { int ab = a3 + 2; if (ab >= 3) ab -= 3; QKV_STAGE_A(kt + 2, ab); }
    if (kt < 14)       WAITV(11);
    else if (kt == 14) WAITV(7);
    else               WAITV(0);
    __builtin_amdgcn_s_barrier();
    __builtin_amdgcn_sched_barrier(0);
    const u16* Ac = &As[a3][0];
    const u16* Bc = &Bs[kt & 1][0];
    #pragma unroll
    for (int kk = 0; kk < 2; ++kk) {
      bf16x8 af[8], bfr[3];
      #pragma unroll
      for (int m = 0; m < 8; ++m)
        af[m] = *(const bf16x8*)&Ac[(wm*128 + m*16 + qi)*64 + ((kk*32 + g*8) ^ xq)];
      #pragma unroll
      for (int n = 0; n < 3; ++n)
        bfr[n] = *(const bf16x8*)&Bc[(wn*48 + n*16 + qi)*64 + ((kk*32 + g*8) ^ xq)];
      #pragma unroll
      for (int m = 0; m < 8; ++m)
        #pragma unroll
        for (int n = 0; n < 3; ++n)
          acc[m][n] = __builtin_amdgcn_mfma_f32_16x16x32_bf16(af[m], bfr[n], acc[m][n], 0, 0, 0);
    }
    __builtin_amdgcn_s_barrier();
    a3 = (a3 == 2) ? 0 : a3 + 1;
  }
#undef QKV_STAGE_A
#undef QKV_STAGE_B

  #pragma unroll
  for (int m = 0; m < 8; ++m) {
    const int row0 = bm*256 + wm*128 + m*16 + g*4;
    const int bb = row0 >> 11;
    const int t0 = row0 & 2047;
    #pragma unroll
    for (int n = 0; n < 3; ++n) {
      const int col = bn*192 + wn*48 + n*16 + qi;
      const float bv = bias[col];
      const int which = col >> 10;      // 0=q 1=k 2=v
      const int cc = col & 1023;
      const int h = cc >> 6, d = cc & 63;
      const int bh = bb*16 + h;
      if (which == 2) {
        ushort4 pw;
        pw.x = f2b(acc[m][n][0] + bv);
        pw.y = f2b(acc[m][n][1] + bv);
        pw.z = f2b(acc[m][n][2] + bv);
        pw.w = f2b(acc[m][n][3] + bv);
        *(ushort4*)&vtb[((size_t)bh*HDIM + d)*SEQ + t0] = pw;
      } else {
        u16* dst = (which == 0) ? qbo : kb;
        #pragma unroll
        for (int r = 0; r < 4; ++r)
          dst[((size_t)bh*SEQ + t0 + r)*HDIM + d] = f2b(acc[m][n][r] + bv);
      }
    }
  }
}

// ---------- proj GEMM: out[4096][1024] f32 = y * wpt^T + b (unchanged R9) ---
__global__ __launch_bounds__(256) void csa_gemm_proj(
    const u16* __restrict__ A, const u16* __restrict__ Bt,
    const float* __restrict__ bias, float* __restrict__ out)
{
  __shared__ __align__(16) u16 As[3][128*64];   // 48 KB
  __shared__ __align__(16) u16 Bs[2][128*64];   // 32 KB
  const int t = threadIdx.x, lane = t & 63, w = t >> 6;
  const int wm = w >> 1, wn = w & 1, g = lane >> 4, qi = lane & 15;
  const int xq = (qi & 7) * 8;
  const int bm = blockIdx.y, bn = blockIdx.x;

  f32x4 acc[4][4] = {};

  const u16* Ab = A  + (size_t)(bm*128)*CH;
  const u16* Bb = Bt + (size_t)(bn*128)*CH;
  const int srow = t >> 3;                               // 0..31
  const int scolsw = ((t & 7) * 8) ^ ((srow & 7) * 8);

#define PRJ_STAGE(P_, base_, kt_, buf_) do { const size_t k_ = (size_t)(kt_)*64;      \
    gload_lds16(P_ + (size_t)( 0 + srow)*CH + k_ + scolsw, &base_[buf_][     w*512]); \
    gload_lds16(P_ + (size_t)(32 + srow)*CH + k_ + scolsw, &base_[buf_][2048+w*512]); \
    gload_lds16(P_ + (size_t)(64 + srow)*CH + k_ + scolsw, &base_[buf_][4096+w*512]); \
    gload_lds16(P_ + (size_t)(96 + srow)*CH + k_ + scolsw, &base_[buf_][6144+w*512]); \
  } while (0)

  PRJ_STAGE(Ab, As, 0, 0); PRJ_STAGE(Bb, Bs, 0, 0); PRJ_STAGE(Ab, As, 1, 1);

  int a3 = 0;
  for (int kt = 0; kt < 16; ++kt) {
    if (kt < 15) PRJ_STAGE(Bb, Bs, kt + 1, (kt + 1) & 1);
    if (kt < 14) { int ab = a3 + 2; if (ab >= 3) ab -= 3; PRJ_STAGE(Ab, As, kt + 2, ab); }
    if (kt < 14)       WAITV(12);
    else if (kt == 14) WAITV(8);
    else               WAITV(0);
    __builtin_amdgcn_s_barrier();
    __builtin_amdgcn_sched_barrier(0);
    const u16* Ac = &As[a3][0];
    const u16* Bc = &Bs[kt & 1][0];
    #pragma unroll
    for (int kk = 0; kk < 2; ++kk) {
      bf16x8 af[4], bfr[4];
      #pragma unroll
      for (int m = 0; m < 4; ++m)
        af[m] = *(const bf16x8*)&Ac[(wm*64 + m*16 + qi)*64 + ((kk*32 + g*8) ^ xq)];
      #pragma unroll
      for (int n = 0; n < 4; ++n)
        bfr[n] = *(const bf16x8*)&Bc[(wn*64 + n*16 + qi)*64 + ((kk*32 + g*8) ^ xq)];
      #pragma unroll
      for (int m = 0; m < 4; ++m)
        #pragma unroll
        for (int n = 0; n < 4; ++n)
          acc[m][n] = __builtin_amdgcn_mfma_f32_16x16x32_bf16(af[m], bfr[n], acc[m][n], 0, 0, 0);
    }
    __builtin_amdgcn_s_barrier();
    a3 = (a3 == 2) ? 0 : a3 + 1;
  }
#undef PRJ_STAGE

  #pragma unroll
  for (int m = 0; m < 4; ++m) {
    const int row0 = bm*128 + wm*64 + m*16 + g*4;
    #pragma unroll
    for (int n = 0; n < 4; ++n) {
      const int col = bn*128 + wn*64 + n*16 + qi;
      const float bv = bias[col];
      #pragma unroll
      for (int r = 0; r < 4; ++r)
        out[(size_t)(row0 + r)*CH + col] = acc[m][n][r] + bv;
    }
  }
}

// ---------- causal flash attention v8: 32x32 + in-reg P + 2 blocks/CU -------
// grid 32 x 16, 512 thr = 8 waves; ONE q-tile (128 rows) per block,
// qt = (y<8) ? y : 23-y so the two co-resident blocks per CU sum to a
// uniform 17 iterations (anti-lockstep: two independent barrier groups per
// CU; one block's softmax VALU overlaps the other's MFMA).
// __launch_bounds__(512,4) pins VGPR<=128 so 2-block residency holds
// (LDS 68.6KB x 2 = 137KB <= 160KB). Internals = v7 (verified correct):
// swapped QK^T 32x32x16, in-register P via cvt_pk+permlane32_swap (T12),
// wave-pair key-split with epilogue flash-combine. Tree max/sum (4-way)
// shortens the serial softmax chains 32 -> ~10 deep.
__global__ __launch_bounds__(512, 4) void csa_attn(
    const u16* __restrict__ qb, const u16* __restrict__ kb,
    const u16* __restrict__ vtb, u16* __restrict__ yout)
{
  const int bh = blockIdx.x, y = blockIdx.y;
  const int qt = (y < 8) ? y : 23 - y;
  const int bidx = bh >> 4, h = bh & 15;
  const int t = threadIdx.x, lane = t & 63, w = t >> 6;   // w 0..7
  const int j = w >> 1, sub = w & 1;
  const int l31 = lane & 31, hi = lane >> 5;

  __shared__ __align__(16) u16 Ks[2][128*64];   // 32 KB [key][d] swizzled
  __shared__ __align__(16) u16 Vs[2][64*128];   // 32 KB [d][key] slot-swizzled
  __shared__ float mtab[8][32], stab[8][32], ftab[8][32];

  const size_t kvbase = (size_t)bh * SEQ * HDIM;
  const u16* kb_bh  = kb  + kvbase;
  const u16* vtb_bh = vtb + kvbase;

  const int krow = t >> 3;                        // 0..63
  const int kcol = 8 * ((t & 7) ^ (krow & 7));
  const int vrow = t >> 4;                        // 0..31
  const int vcol = 8 * ((t & 15) ^ (vrow & 15));

#define ATTN_STAGE(kt_, b_) do {                                             \
    const u16* kp_ = kb_bh + (size_t)((kt_)*128 + krow)*64 + kcol;           \
    gload_lds16(kp_,           &Ks[b_][       w*512]);                       \
    gload_lds16(kp_ + 64*64,   &Ks[b_][4096 + w*512]);                       \
    const u16* vp_ = vtb_bh + (size_t)vrow*SEQ + (kt_)*128 + vcol;           \
    gload_lds16(vp_,           &Vs[b_][       w*512]);                       \
    gload_lds16(vp_ + 32*SEQ,  &Vs[b_][4096 + w*512]);                       \
  } while (0)

  int offK[2][4];
  #pragma unroll
  for (int kb2 = 0; kb2 < 2; ++kb2)
    #pragma unroll
    for (int ds = 0; ds < 4; ++ds)
      offK[kb2][ds] = (sub*64 + kb2*32 + l31)*64 + ((ds*16 + hi*8) ^ ((l31 & 7)*8));
  int offV[2][4];
  #pragma unroll
  for (int db = 0; db < 2; ++db)
    #pragma unroll
    for (int ks = 0; ks < 4; ++ks)
      offV[db][ks] = (db*32 + l31)*128 + (((sub*8 + 2*ks + hi) ^ (l31 & 15))*8);

#define PACK(ps_, b_, out_) do {                                             \
    unsigned A0_ = cvt_pk_bf16(ps_[(b_)+0], ps_[(b_)+1]);                    \
    unsigned A1_ = cvt_pk_bf16(ps_[(b_)+2], ps_[(b_)+3]);                    \
    unsigned B0_ = cvt_pk_bf16(ps_[(b_)+4], ps_[(b_)+5]);                    \
    unsigned B1_ = cvt_pk_bf16(ps_[(b_)+6], ps_[(b_)+7]);                    \
    asm volatile("v_permlane32_swap_b32 %0, %1" : "+v"(A0_), "+v"(B0_));     \
    asm volatile("v_permlane32_swap_b32 %0, %1" : "+v"(A1_), "+v"(B1_));     \
    union { unsigned u[4]; bf16x8 v; } pu_;                                  \
    pu_.u[0] = A0_; pu_.u[1] = A1_; pu_.u[2] = B0_; pu_.u[3] = B1_;          \
    out_ = pu_.v;                                                            \
  } while (0)

  const float QSCALE = 0.18033688011112042f;   // 0.125 * log2(e)
  const int qloc = j*32 + l31;
  const int ntile = qt + 1;
  const int qrow = qt*128 + j*32;

  // Q B-operand: col=lane&31=q, k=(lane>>5)*8+e; pre-scaled (exp2 domain)
  bf16x8 qf[4];
  #pragma unroll
  for (int ds = 0; ds < 4; ++ds) {
    qf[ds] = *(const bf16x8*)&qb[kvbase + (size_t)(qrow + l31)*HDIM + ds*16 + hi*8];
    #pragma unroll
    for (int e = 0; e < 8; ++e)
      qf[ds][e] = (short)f2b(b2f((u16)qf[ds][e]) * QSCALE);
  }

  f32x16 yacc0 = {}, yacc1 = {};        // O[d-block 0/1]: row=q=crow, col=d
  float mrun = -1e30f, srun = 0.f;      // per-lane (q = l31), pair-synced m

  ATTN_STAGE(0, 0);
  __syncthreads();

  int buf = 0;
  for (int kt = 0; kt < ntile; ++kt) {
    if (kt + 1 < ntile) ATTN_STAGE(kt + 1, buf ^ 1);

    // S^T = K * Q^T (two 32-key blocks of this wave's 64-key half)
    f32x16 s0 = {}, s1 = {};
    #pragma unroll
    for (int ds = 0; ds < 4; ++ds) {
      bf16x8 k0 = *(const bf16x8*)&Ks[buf][offK[0][ds]];
      s0 = __builtin_amdgcn_mfma_f32_32x32x16_bf16(k0, qf[ds], s0, 0, 0, 0);
      bf16x8 k1 = *(const bf16x8*)&Ks[buf][offK[1][ds]];
      s1 = __builtin_amdgcn_mfma_f32_32x32x16_bf16(k1, qf[ds], s1, 0, 0, 0);
    }

    // causal mask on the diagonal 128-key tile
    if (kt == ntile - 1) {
      #pragma unroll
      for (int reg = 0; reg < 16; ++reg) {
        const int cr = (reg & 3) + 8*(reg >> 2) + 4*hi;
        if (sub*64 + cr > qloc)      s0[reg] = -3.0e38f;
        if (sub*64 + 32 + cr > qloc) s1[reg] = -3.0e38f;
      }
    }

    // online softmax (exp2 domain), defer-max; 4-way tree max (short chain)
    float t0 = fmaxf(s0[0], s1[0]), t1 = fmaxf(s0[1], s1[1]);
    float t2 = fmaxf(s0[2], s1[2]), t3 = fmaxf(s0[3], s1[3]);
    #pragma unroll
    for (int reg = 4; reg < 16; reg += 4) {
      t0 = fmaxf(t0, fmaxf(s0[reg+0], s1[reg+0]));
      t1 = fmaxf(t1, fmaxf(s0[reg+1], s1[reg+1]));
      t2 = fmaxf(t2, fmaxf(s0[reg+2], s1[reg+2]));
      t3 = fmaxf(t3, fmaxf(s0[reg+3], s1[reg+3]));
    }
    float tmax = fmaxf(fmaxf(t0, t1), fmaxf(t2, t3));
    if (!__all(tmax - mrun <= 11.5f)) {       // rare true rescale
      float tmf = fmaxf(tmax, __shfl_xor(tmax, 32));
      float mnew = fmaxf(mrun, tmf);
      float fac = exp2_fast(mrun - mnew);
      if (lane < 32) ftab[w][l31] = fac;      // q-indexed -> crow-indexed
      #pragma unroll
      for (int reg = 0; reg < 16; ++reg) {
        float fr = ftab[w][(reg & 3) + 8*(reg >> 2) + 4*hi];
        yacc0[reg] *= fr; yacc1[reg] *= fr;
      }
      srun *= fac; mrun = mnew;
    }
    // exp2 + 4-way tree sum
    float u0 = 0.f, u1 = 0.f, u2 = 0.f, u3 = 0.f;
    #pragma unroll
    for (int reg = 0; reg < 16; reg += 4) {
      float p00 = exp2_fast(s0[reg+0] - mrun), p10 = exp2_fast(s1[reg+0] - mrun);
      float p01 = exp2_fast(s0[reg+1] - mrun), p11 = exp2_fast(s1[reg+1] - mrun);
      float p02 = exp2_fast(s0[reg+2] - mrun), p12 = exp2_fast(s1[reg+2] - mrun);
      float p03 = exp2_fast(s0[reg+3] - mrun), p13 = exp2_fast(s1[reg+3] - mrun);
      s0[reg+0] = p00; s1[reg+0] = p10; u0 += p00 + p10;
      s0[reg+1] = p01; s1[reg+1] = p11; u1 += p01 + p11;
      s0[reg+2] = p02; s1[reg+2] = p12; u2 += p02 + p12;
      s0[reg+3] = p03; s1[reg+3] = p13; u3 += p03 + p13;
    }
    srun += (u0 + u1) + (u2 + u3);

    // T12: in-register P -> PV A-fragments (keys ks*16 + hi*8 + e)
    bf16x8 pa0, pa1, pa2, pa3;
    PACK(s0, 0, pa0); PACK(s0, 8, pa1); PACK(s1, 0, pa2); PACK(s1, 8, pa3);

    // O += P * V
    yacc0 = __builtin_amdgcn_mfma_f32_32x32x16_bf16(pa0, *(const bf16x8*)&Vs[buf][offV[0][0]], yacc0, 0, 0, 0);
    yacc0 = __builtin_amdgcn_mfma_f32_32x32x16_bf16(pa1, *(const bf16x8*)&Vs[buf][offV[0][1]], yacc0, 0, 0, 0);
    yacc0 = __builtin_amdgcn_mfma_f32_32x32x16_bf16(pa2, *(const bf16x8*)&Vs[buf][offV[0][2]], yacc0, 0, 0, 0);
    yacc0 = __builtin_amdgcn_mfma_f32_32x32x16_bf16(pa3, *(const bf16x8*)&Vs[buf][offV[0][3]], yacc0, 0, 0, 0);
    yacc1 = __builtin_amdgcn_mfma_f32_32x32x16_bf16(pa0, *(const bf16x8*)&Vs[buf][offV[1][0]], yacc1, 0, 0, 0);
    yacc1 = __builtin_amdgcn_mfma_f32_32x32x16_bf16(pa1, *(const bf16x8*)&Vs[buf][offV[1][1]], yacc1, 0, 0, 0);
    yacc1 = __builtin_amdgcn_mfma_f32_32x32x16_bf16(pa2, *(const bf16x8*)&Vs[buf][offV[1][2]], yacc1, 0, 0, 0);
    yacc1 = __builtin_amdgcn_mfma_f32_32x32x16_bf16(pa3, *(const bf16x8*)&Vs[buf][offV[1][3]], yacc1, 0, 0, 0);

    __syncthreads();
    buf ^= 1;
  }

  // epilogue: flash-combine the wave pair (sub 0 + sub 1)
  float sfull = srun + __shfl_xor(srun, 32);
  if (lane < 32) { mtab[w][l31] = mrun; stab[w][l31] = sfull; }
  __syncthreads();

  float* Ocomb = (float*)&Ks[0][0];     // [4][32 q][64 d] f32 = 32 KB
  const int wA = w & ~1, wB = w | 1;
  if (sub == 1) {
    #pragma unroll
    for (int reg = 0; reg < 16; ++reg) {
      const int cr = (reg & 3) + 8*(reg >> 2) + 4*hi;
      float mA = mtab[wA][cr], mB = mtab[wB][cr];
      float fB = exp2_fast(mB - fmaxf(mA, mB));
      Ocomb[(j*32 + cr)*64 +      l31] = yacc0[reg] * fB;
      Ocomb[(j*32 + cr)*64 + 32 + l31] = yacc1[reg] * fB;
    }
  }
  __syncthreads();
  if (sub == 0) {
    #pragma unroll
    for (int reg = 0; reg < 16; ++reg) {
      const int cr = (reg & 3) + 8*(reg >> 2) + 4*hi;
      float mA = mtab[wA][cr], mB = mtab[wB][cr];
      float sA = stab[wA][cr], sB = stab[wB][cr];
      float ms = fmaxf(mA, mB);
      float fA = exp2_fast(mA - ms), fB = exp2_fast(mB - ms);
      float inv = 1.f / (sA * fA + sB * fB);
      const size_t orow = ((size_t)bidx*SEQ + qt*128 + j*32 + cr)*CH + h*HDIM;
      float v0 = (yacc0[reg] * fA + Ocomb[(j*32 + cr)*64 +      l31]) * inv;
      float v1 = (yacc1[reg] * fA + Ocomb[(j*32 + cr)*64 + 32 + l31]) * inv;
      yout[orow +      l31] = f2b(v0);
      yout[orow + 32 + l31] = f2b(v1);
    }
  }
#undef ATTN_STAGE
#undef PACK
}

extern "C" void kernel_launch(void* const* d_in, const int* in_sizes, int n_in,
                              void* d_out, int out_size, void* d_ws, size_t ws_size,
                              hipStream_t stream) {
  (void)in_sizes; (void)n_in; (void)out_size; (void)ws_size;
  const float* x      = (const float*)d_in[0];
  const float* w_attn = (const float*)d_in[1];
  const float* b_attn = (const float*)d_in[2];
  const float* w_proj = (const float*)d_in[3];
  const float* b_proj = (const float*)d_in[4];

  char* ws = (char*)d_ws;
  const size_t MB = 1024*1024;
  u16* xb  = (u16*)(ws);             // 8 MB, reused as attention out y
  u16* wat = (u16*)(ws +  8*MB);     // 6 MB  w_attn^T [3072][1024]
  u16* wpt = (u16*)(ws + 14*MB);     // 2 MB  w_proj^T [1024][1024]
  u16* qb  = (u16*)(ws + 16*MB);     // 8 MB  [bh][t][64]
  u16* kb  = (u16*)(ws + 24*MB);     // 8 MB  [bh][t][64]
  u16* vtb = (u16*)(ws + 32*MB);     // 8 MB  [bh][64][t]

  csa_prep<<<6144, 256, 0, stream>>>(x, w_attn, w_proj, xb, wat, wpt);
  csa_gemm_qkv<<<dim3(16, 16), 512, 0, stream>>>(xb, wat, b_attn, qb, kb, vtb);
  csa_attn<<<dim3(32, 16), 512, 0, stream>>>(qb, kb, vtb, xb);
  csa_gemm_proj<<<dim3(8, 32), 256, 0, stream>>>(xb, wpt, b_proj, (float*)d_out);
}

// Round 13
// 102.460 us; speedup vs baseline: 1.0238x; 1.0030x over previous
//
#include <hip/hip_runtime.h>

typedef unsigned short u16;
typedef short bf16x8 __attribute__((ext_vector_type(8)));
typedef float f32x4 __attribute__((ext_vector_type(4)));
typedef float f32x16 __attribute__((ext_vector_type(16)));

#define BATCH 2
#define SEQ   2048
#define CH    1024
#define NHEAD 16
#define HDIM  64
#define ROWS  (BATCH*SEQ)   // 4096

#define WAITV(N) asm volatile("s_waitcnt vmcnt(" #N ")" ::: "memory")

__device__ __forceinline__ u16 f2b(float f) {
  unsigned u = __builtin_bit_cast(unsigned, f);
  u += 0x7FFFu + ((u >> 16) & 1u);
  return (u16)(u >> 16);
}
__device__ __forceinline__ float b2f(u16 h) {
  unsigned u = ((unsigned)h) << 16;
  return __builtin_bit_cast(float, u);
}
__device__ __forceinline__ float exp2_fast(float x) {
  float r; asm("v_exp_f32 %0, %1" : "=v"(r) : "v"(x)); return r;
}
__device__ __forceinline__ unsigned cvt_pk_bf16(float a, float b) {
  unsigned r; asm("v_cvt_pk_bf16_f32 %0, %1, %2" : "=v"(r) : "v"(a), "v"(b)); return r;
}

__device__ __forceinline__ void gload_lds16(const void* g, void* l) {
  __builtin_amdgcn_global_load_lds(
      (const __attribute__((address_space(1))) unsigned int*)g,
      (__attribute__((address_space(3))) unsigned int*)l, 16, 0, 0);
}

// ---------- fused prep: x f32->bf16, both weight transposes (one launch) ----
__global__ void csa_prep(const float* __restrict__ x,
                         const float* __restrict__ wa, const float* __restrict__ wp,
                         u16* __restrict__ xb, u16* __restrict__ wat,
                         u16* __restrict__ wpt) {
  __shared__ float tile[32][33];
  const int b = blockIdx.x, t = threadIdx.x;
  if (b < 2048) {               // convert x: 524288 uint4-pairs
    int i = b * 256 + t;
    const float4* f4 = (const float4*)x;
    float4 v0 = f4[2*i], v1 = f4[2*i+1];
    ushort4 o0, o1;
    o0.x = f2b(v0.x); o0.y = f2b(v0.y); o0.z = f2b(v0.z); o0.w = f2b(v0.w);
    o1.x = f2b(v1.x); o1.y = f2b(v1.y); o1.z = f2b(v1.z); o1.w = f2b(v1.w);
    ((ushort4*)xb)[2*i]   = o0;
    ((ushort4*)xb)[2*i+1] = o1;
    return;
  }
  int bb = b - 2048;            // transpose: 4096 blocks (128 x 32)
  int bx = bb & 127, by = bb >> 7;
  const float* in; u16* out; int C;
  if (bx < 96) { in = wa; out = wat; C = 3*CH; }
  else         { in = wp; out = wpt; C = CH; bx -= 96; }
  const int R = CH;
  const int bxc = bx * 32, byc = by * 32;
  const int tx = t & 31, ty = t >> 5;
  #pragma unroll
  for (int j = 0; j < 4; ++j) {
    int r = byc + ty + j*8, c = bxc + tx;
    tile[ty + j*8][tx] = in[(size_t)r*C + c];
  }
  __syncthreads();
  #pragma unroll
  for (int j = 0; j < 4; ++j) {
    int oc = bxc + ty + j*8;
    int orr = byc + tx;
    out[(size_t)oc*R + orr] = f2b(tile[tx][ty + j*8]);
  }
}

// ---------- QKV GEMM: [4096][3072] = xb * wat^T + b (unchanged from R9) -----
__global__ __launch_bounds__(512) void csa_gemm_qkv(
    const u16* __restrict__ A, const u16* __restrict__ Bt,
    const float* __restrict__ bias,
    u16* __restrict__ qbo, u16* __restrict__ kb, u16* __restrict__ vtb)
{
  __shared__ __align__(16) u16 As[3][256*64];   // 96 KB
  __shared__ __align__(16) u16 Bs[2][192*64];   // 48 KB
  const int t = threadIdx.x, lane = t & 63, w = t >> 6;
  const int wm = w >> 2, wn = w & 3, g = lane >> 4, qi = lane & 15;
  const int xq = (qi & 7) * 8;

  const int wgid = blockIdx.y * 16 + blockIdx.x;
  const int c8 = wgid & 7, inner = wgid >> 3;
  const int bm = (c8 >> 1) * 4 + (inner >> 3);
  const int bn = (c8 & 1) * 8 + (inner & 7);

  f32x4 acc[8][3] = {};

  const u16* Ab = A  + (size_t)(bm*256)*CH;
  const u16* Bb = Bt + (size_t)(bn*192)*CH;
  const int srow = t >> 3;                               // 0..63
  const int scolsw = ((t & 7) * 8) ^ ((srow & 7) * 8);   // pre-swizzled src col

#define QKV_STAGE_A(kt_, buf_) do { const size_t k_ = (size_t)(kt_)*64;            \
    gload_lds16(Ab + (size_t)(  0 + srow)*CH + k_ + scolsw, &As[buf_][      w*512]); \
    gload_lds16(Ab + (size_t)( 64 + srow)*CH + k_ + scolsw, &As[buf_][ 4096+w*512]); \
    gload_lds16(Ab + (size_t)(128 + srow)*CH + k_ + scolsw, &As[buf_][ 8192+w*512]); \
    gload_lds16(Ab + (size_t)(192 + srow)*CH + k_ + scolsw, &As[buf_][12288+w*512]); \
  } while (0)
#define QKV_STAGE_B(kt_, buf_) do { const size_t k_ = (size_t)(kt_)*64;            \
    gload_lds16(Bb + (size_t)(  0 + srow)*CH + k_ + scolsw, &Bs[buf_][      w*512]); \
    gload_lds16(Bb + (size_t)( 64 + srow)*CH + k_ + scolsw, &Bs[buf_][ 4096+w*512]); \
    gload_lds16(Bb + (size_t)(128 + srow)*CH + k_ + scolsw, &Bs[buf_][ 8192+w*512]); \
  } while (0)

  QKV_STAGE_A(0, 0); QKV_STAGE_B(0, 0); QKV_STAGE_A(1, 1);

  int a3 = 0;
  for (int kt = 0; kt < 16; ++kt) {
    if (kt < 15) QKV_STAGE_B(kt + 1, (kt + 1) & 1);
    if (kt < 14) { int ab = a3 + 2; if (ab >= 3) ab -= 3; QKV_STAGE_A(kt + 2, ab); }
    if (kt < 14)       WAITV(11);
    else if (kt == 14) WAITV(7);
    else               WAITV(0);
    __builtin_amdgcn_s_barrier();
    __builtin_amdgcn_sched_barrier(0);
    const u16* Ac = &As[a3][0];
    const u16* Bc = &Bs[kt & 1][0];
    #pragma unroll
    for (int kk = 0; kk < 2; ++kk) {
      bf16x8 af[8], bfr[3];
      #pragma unroll
      for (int m = 0; m < 8; ++m)
        af[m] = *(const bf16x8*)&Ac[(wm*128 + m*16 + qi)*64 + ((kk*32 + g*8) ^ xq)];
      #pragma unroll
      for (int n = 0; n < 3; ++n)
        bfr[n] = *(const bf16x8*)&Bc[(wn*48 + n*16 + qi)*64 + ((kk*32 + g*8) ^ xq)];
      #pragma unroll
      for (int m = 0; m < 8; ++m)
        #pragma unroll
        for (int n = 0; n < 3; ++n)
          acc[m][n] = __builtin_amdgcn_mfma_f32_16x16x32_bf16(af[m], bfr[n], acc[m][n], 0, 0, 0);
    }
    __builtin_amdgcn_s_barrier();
    a3 = (a3 == 2) ? 0 : a3 + 1;
  }
#undef QKV_STAGE_A
#undef QKV_STAGE_B

  #pragma unroll
  for (int m = 0; m < 8; ++m) {
    const int row0 = bm*256 + wm*128 + m*16 + g*4;
    const int bb = row0 >> 11;
    const int t0 = row0 & 2047;
    #pragma unroll
    for (int n = 0; n < 3; ++n) {
      const int col = bn*192 + wn*48 + n*16 + qi;
      const float bv = bias[col];
      const int which = col >> 10;      // 0=q 1=k 2=v
      const int cc = col & 1023;
      const int h = cc >> 6, d = cc & 63;
      const int bh = bb*16 + h;
      if (which == 2) {
        ushort4 pw;
        pw.x = f2b(acc[m][n][0] + bv);
        pw.y = f2b(acc[m][n][1] + bv);
        pw.z = f2b(acc[m][n][2] + bv);
        pw.w = f2b(acc[m][n][3] + bv);
        *(ushort4*)&vtb[((size_t)bh*HDIM + d)*SEQ + t0] = pw;
      } else {
        u16* dst = (which == 0) ? qbo : kb;
        #pragma unroll
        for (int r = 0; r < 4; ++r)
          dst[((size_t)bh*SEQ + t0 + r)*HDIM + d] = f2b(acc[m][n][r] + bv);
      }
    }
  }
}

// ---------- proj GEMM: out[4096][1024] f32 = y * wpt^T + b (unchanged R9) ---
__global__ __launch_bounds__(256) void csa_gemm_proj(
    const u16* __restrict__ A, const u16* __restrict__ Bt,
    const float* __restrict__ bias, float* __restrict__ out)
{
  __shared__ __align__(16) u16 As[3][128*64];   // 48 KB
  __shared__ __align__(16) u16 Bs[2][128*64];   // 32 KB
  const int t = threadIdx.x, lane = t & 63, w = t >> 6;
  const int wm = w >> 1, wn = w & 1, g = lane >> 4, qi = lane & 15;
  const int xq = (qi & 7) * 8;
  const int bm = blockIdx.y, bn = blockIdx.x;

  f32x4 acc[4][4] = {};

  const u16* Ab = A  + (size_t)(bm*128)*CH;
  const u16* Bb = Bt + (size_t)(bn*128)*CH;
  const int srow = t >> 3;                               // 0..31
  const int scolsw = ((t & 7) * 8) ^ ((srow & 7) * 8);

#define PRJ_STAGE(P_, base_, kt_, buf_) do { const size_t k_ = (size_t)(kt_)*64;      \
    gload_lds16(P_ + (size_t)( 0 + srow)*CH + k_ + scolsw, &base_[buf_][     w*512]); \
    gload_lds16(P_ + (size_t)(32 + srow)*CH + k_ + scolsw, &base_[buf_][2048+w*512]); \
    gload_lds16(P_ + (size_t)(64 + srow)*CH + k_ + scolsw, &base_[buf_][4096+w*512]); \
    gload_lds16(P_ + (size_t)(96 + srow)*CH + k_ + scolsw, &base_[buf_][6144+w*512]); \
  } while (0)

  PRJ_STAGE(Ab, As, 0, 0); PRJ_STAGE(Bb, Bs, 0, 0); PRJ_STAGE(Ab, As, 1, 1);

  int a3 = 0;
  for (int kt = 0; kt < 16; ++kt) {
    if (kt < 15) PRJ_STAGE(Bb, Bs, kt + 1, (kt + 1) & 1);
    if (kt < 14) { int ab = a3 + 2; if (ab >= 3) ab -= 3; PRJ_STAGE(Ab, As, kt + 2, ab); }
    if (kt < 14)       WAITV(12);
    else if (kt == 14) WAITV(8);
    else               WAITV(0);
    __builtin_amdgcn_s_barrier();
    __builtin_amdgcn_sched_barrier(0);
    const u16* Ac = &As[a3][0];
    const u16* Bc = &Bs[kt & 1][0];
    #pragma unroll
    for (int kk = 0; kk < 2; ++kk) {
      bf16x8 af[4], bfr[4];
      #pragma unroll
      for (int m = 0; m < 4; ++m)
        af[m] = *(const bf16x8*)&Ac[(wm*64 + m*16 + qi)*64 + ((kk*32 + g*8) ^ xq)];
      #pragma unroll
      for (int n = 0; n < 4; ++n)
        bfr[n] = *(const bf16x8*)&Bc[(wn*64 + n*16 + qi)*64 + ((kk*32 + g*8) ^ xq)];
      #pragma unroll
      for (int m = 0; m < 4; ++m)
        #pragma unroll
        for (int n = 0; n < 4; ++n)
          acc[m][n] = __builtin_amdgcn_mfma_f32_16x16x32_bf16(af[m], bfr[n], acc[m][n], 0, 0, 0);
    }
    __builtin_amdgcn_s_barrier();
    a3 = (a3 == 2) ? 0 : a3 + 1;
  }
#undef PRJ_STAGE

  #pragma unroll
  for (int m = 0; m < 4; ++m) {
    const int row0 = bm*128 + wm*64 + m*16 + g*4;
    #pragma unroll
    for (int n = 0; n < 4; ++n) {
      const int col = bn*128 + wn*64 + n*16 + qi;
      const float bv = bias[col];
      #pragma unroll
      for (int r = 0; r < 4; ++r)
        out[(size_t)(row0 + r)*CH + col] = acc[m][n][r] + bv;
    }
  }
}

// ---------- causal flash attention v9: VALU diet -----------------------------
// v8 structure (32x32 MFMA, in-reg P via cvt_pk+permlane, wave-pair key-split,
// single-barrier dbuf) + three VALU cuts:
//  1. msplat C-init: first QK MFMA takes C = splat(-mrun) (C col=q=lane matches
//     mrun's per-lane q) -> S exits the matrix pipe pre-shifted; deletes 32
//     v_sub/iter. mrun init = 0 (defer-max with initial guess 0; rescale path
//     handles any data). msplat rebuilt only in the rare rescale branch.
//  2. ones-B MFMA row-sum: ones_acc accumulates sum_k P across ALL iterations
//     on the matrix pipe (rescaled with yacc); deletes 32 v_add + tree/iter;
//     denominator = exact sum of the same bf16 P used in the numerator.
//  3. max3-shaped reduction tree (fmaxf nests fuse to v_max3).
__global__ __launch_bounds__(512, 2) void csa_attn(
    const u16* __restrict__ qb, const u16* __restrict__ kb,
    const u16* __restrict__ vtb, u16* __restrict__ yout)
{
  const int bh = blockIdx.x, y = blockIdx.y;
  const int qt = (y < 8) ? y : 23 - y;
  const int bidx = bh >> 4, h = bh & 15;
  const int t = threadIdx.x, lane = t & 63, w = t >> 6;   // w 0..7
  const int j = w >> 1, sub = w & 1;
  const int l31 = lane & 31, hi = lane >> 5;

  __shared__ __align__(16) u16 Ks[2][128*64];   // 32 KB [key][d] swizzled
  __shared__ __align__(16) u16 Vs[2][64*128];   // 32 KB [d][key] slot-swizzled
  __shared__ float mtab[8][32], stab[8][32], ftab[8][32];

  const size_t kvbase = (size_t)bh * SEQ * HDIM;
  const u16* kb_bh  = kb  + kvbase;
  const u16* vtb_bh = vtb + kvbase;

  const int krow = t >> 3;                        // 0..63
  const int kcol = 8 * ((t & 7) ^ (krow & 7));
  const int vrow = t >> 4;                        // 0..31
  const int vcol = 8 * ((t & 15) ^ (vrow & 15));

#define ATTN_STAGE(kt_, b_) do {                                             \
    const u16* kp_ = kb_bh + (size_t)((kt_)*128 + krow)*64 + kcol;           \
    gload_lds16(kp_,           &Ks[b_][       w*512]);                       \
    gload_lds16(kp_ + 64*64,   &Ks[b_][4096 + w*512]);                       \
    const u16* vp_ = vtb_bh + (size_t)vrow*SEQ + (kt_)*128 + vcol;           \
    gload_lds16(vp_,           &Vs[b_][       w*512]);                       \
    gload_lds16(vp_ + 32*SEQ,  &Vs[b_][4096 + w*512]);                       \
  } while (0)

  int offK[2][4];
  #pragma unroll
  for (int kb2 = 0; kb2 < 2; ++kb2)
    #pragma unroll
    for (int ds = 0; ds < 4; ++ds)
      offK[kb2][ds] = (sub*64 + kb2*32 + l31)*64 + ((ds*16 + hi*8) ^ ((l31 & 7)*8));
  int offV[2][4];
  #pragma unroll
  for (int db = 0; db < 2; ++db)
    #pragma unroll
    for (int ks = 0; ks < 4; ++ks)
      offV[db][ks] = (db*32 + l31)*128 + (((sub*8 + 2*ks + hi) ^ (l31 & 15))*8);

#define PACK(ps_, b_, out_) do {                                             \
    unsigned A0_ = cvt_pk_bf16(ps_[(b_)+0], ps_[(b_)+1]);                    \
    unsigned A1_ = cvt_pk_bf16(ps_[(b_)+2], ps_[(b_)+3]);                    \
    unsigned B0_ = cvt_pk_bf16(ps_[(b_)+4], ps_[(b_)+5]);                    \
    unsigned B1_ = cvt_pk_bf16(ps_[(b_)+6], ps_[(b_)+7]);                    \
    asm volatile("v_permlane32_swap_b32 %0, %1" : "+v"(A0_), "+v"(B0_));     \
    asm volatile("v_permlane32_swap_b32 %0, %1" : "+v"(A1_), "+v"(B1_));     \
    union { unsigned u[4]; bf16x8 v; } pu_;                                  \
    pu_.u[0] = A0_; pu_.u[1] = A1_; pu_.u[2] = B0_; pu_.u[3] = B1_;          \
    out_ = pu_.v;                                                            \
  } while (0)

  const float QSCALE = 0.18033688011112042f;   // 0.125 * log2(e)
  const int qloc = j*32 + l31;
  const int ntile = qt + 1;
  const int qrow = qt*128 + j*32;

  // Q B-operand: col=lane&31=q, k=(lane>>5)*8+e; pre-scaled (exp2 domain)
  bf16x8 qf[4];
  #pragma unroll
  for (int ds = 0; ds < 4; ++ds) {
    qf[ds] = *(const bf16x8*)&qb[kvbase + (size_t)(qrow + l31)*HDIM + ds*16 + hi*8];
    #pragma unroll
    for (int e = 0; e < 8; ++e)
      qf[ds][e] = (short)f2b(b2f((u16)qf[ds][e]) * QSCALE);
  }

  // ones B-operand (layout-independent all-1.0 bf16)
  bf16x8 onesb;
  #pragma unroll
  for (int e = 0; e < 8; ++e) onesb[e] = (short)0x3F80;

  f32x16 yacc0 = {}, yacc1 = {};        // O[d-block 0/1]: row=q=crow, col=d
  f32x16 ones_acc = {};                 // row-sums: D[q=crow][*] = sum_k P
  f32x16 msplat = {};                   // C-init = -mrun (col=q=lane)
  float mrun = 0.f;                     // per-lane (q = l31), pair-synced

  ATTN_STAGE(0, 0);
  __syncthreads();

  int buf = 0;
  for (int kt = 0; kt < ntile; ++kt) {
    if (kt + 1 < ntile) ATTN_STAGE(kt + 1, buf ^ 1);

    // S' = K * Q^T - mrun  (C = msplat; two 32-key blocks of the 64-key half)
    f32x16 s0, s1;
    {
      bf16x8 k00 = *(const bf16x8*)&Ks[buf][offK[0][0]];
      s0 = __builtin_amdgcn_mfma_f32_32x32x16_bf16(k00, qf[0], msplat, 0, 0, 0);
      bf16x8 k10 = *(const bf16x8*)&Ks[buf][offK[1][0]];
      s1 = __builtin_amdgcn_mfma_f32_32x32x16_bf16(k10, qf[0], msplat, 0, 0, 0);
    }
    #pragma unroll
    for (int ds = 1; ds < 4; ++ds) {
      bf16x8 k0 = *(const bf16x8*)&Ks[buf][offK[0][ds]];
      s0 = __builtin_amdgcn_mfma_f32_32x32x16_bf16(k0, qf[ds], s0, 0, 0, 0);
      bf16x8 k1 = *(const bf16x8*)&Ks[buf][offK[1][ds]];
      s1 = __builtin_amdgcn_mfma_f32_32x32x16_bf16(k1, qf[ds], s1, 0, 0, 0);
    }

    // causal mask on the diagonal 128-key tile
    if (kt == ntile - 1) {
      #pragma unroll
      for (int reg = 0; reg < 16; ++reg) {
        const int cr = (reg & 3) + 8*(reg >> 2) + 4*hi;
        if (sub*64 + cr > qloc)      s0[reg] = -3.0e38f;
        if (sub*64 + 32 + cr > qloc) s1[reg] = -3.0e38f;
      }
    }

    // defer-max check on S' (max3-shaped tree)
    float a0 = fmaxf(s0[0], s1[0]), a1 = fmaxf(s0[1], s1[1]);
    float a2 = fmaxf(s0[2], s1[2]), a3 = fmaxf(s0[3], s1[3]);
    #pragma unroll
    for (int reg = 4; reg < 16; reg += 4) {
      a0 = fmaxf(fmaxf(a0, s0[reg+0]), s1[reg+0]);
      a1 = fmaxf(fmaxf(a1, s0[reg+1]), s1[reg+1]);
      a2 = fmaxf(fmaxf(a2, s0[reg+2]), s1[reg+2]);
      a3 = fmaxf(fmaxf(a3, s0[reg+3]), s1[reg+3]);
    }
    float tpart = fmaxf(fmaxf(a0, a1), fmaxf(a2, a3));
    if (!__all(tpart <= 11.5f)) {           // rare true rescale
      float tmf = fmaxf(tpart, __shfl_xor(tpart, 32));
      float delta = fmaxf(tmf, 0.f);        // mnew - mrun
      float fac = exp2_fast(-delta);
      if (lane < 32) ftab[w][l31] = fac;    // q-indexed -> crow-indexed
      #pragma unroll
      for (int reg = 0; reg < 16; ++reg) {
        float fr = ftab[w][(reg & 3) + 8*(reg >> 2) + 4*hi];
        yacc0[reg] *= fr; yacc1[reg] *= fr; ones_acc[reg] *= fr;
      }
      mrun += delta;
      #pragma unroll
      for (int reg = 0; reg < 16; ++reg) {
        msplat[reg] = -mrun;
        s0[reg] -= delta; s1[reg] -= delta;
      }
    }

    // P = exp2(S')  (no sub in common path)
    #pragma unroll
    for (int reg = 0; reg < 16; ++reg) {
      s0[reg] = exp2_fast(s0[reg]);
      s1[reg] = exp2_fast(s1[reg]);
    }

    // T12: in-register P -> PV A-fragments (keys ks*16 + hi*8 + e)
    bf16x8 pa0, pa1, pa2, pa3;
    PACK(s0, 0, pa0); PACK(s0, 8, pa1); PACK(s1, 0, pa2); PACK(s1, 8, pa3);

    // O += P * V ; row-sums accumulate on the matrix pipe (ones-B MFMA)
    yacc0 = __builtin_amdgcn_mfma_f32_32x32x16_bf16(pa0, *(const bf16x8*)&Vs[buf][offV[0][0]], yacc0, 0, 0, 0);
    yacc0 = __builtin_amdgcn_mfma_f32_32x32x16_bf16(pa1, *(const bf16x8*)&Vs[buf][offV[0][1]], yacc0, 0, 0, 0);
    yacc0 = __builtin_amdgcn_mfma_f32_32x32x16_bf16(pa2, *(const bf16x8*)&Vs[buf][offV[0][2]], yacc0, 0, 0, 0);
    yacc0 = __builtin_amdgcn_mfma_f32_32x32x16_bf16(pa3, *(const bf16x8*)&Vs[buf][offV[0][3]], yacc0, 0, 0, 0);
    yacc1 = __builtin_amdgcn_mfma_f32_32x32x16_bf16(pa0, *(const bf16x8*)&Vs[buf][offV[1][0]], yacc1, 0, 0, 0);
    yacc1 = __builtin_amdgcn_mfma_f32_32x32x16_bf16(pa1, *(const bf16x8*)&Vs[buf][offV[1][1]], yacc1, 0, 0, 0);
    yacc1 = __builtin_amdgcn_mfma_f32_32x32x16_bf16(pa2, *(const bf16x8*)&Vs[buf][offV[1][2]], yacc1, 0, 0, 0);
    yacc1 = __builtin_amdgcn_mfma_f32_32x32x16_bf16(pa3, *(const bf16x8*)&Vs[buf][offV[1][3]], yacc1, 0, 0, 0);
    ones_acc = __builtin_amdgcn_mfma_f32_32x32x16_bf16(pa0, onesb, ones_acc, 0, 0, 0);
    ones_acc = __builtin_amdgcn_mfma_f32_32x32x16_bf16(pa1, onesb, ones_acc, 0, 0, 0);
    ones_acc = __builtin_amdgcn_mfma_f32_32x32x16_bf16(pa2, onesb, ones_acc, 0, 0, 0);
    ones_acc = __builtin_amdgcn_mfma_f32_32x32x16_bf16(pa3, onesb, ones_acc, 0, 0, 0);

    __syncthreads();
    buf ^= 1;
  }

  // epilogue: flash-combine the wave pair (sub 0 + sub 1)
  if (lane < 32) mtab[w][l31] = mrun;
  if (l31 == 0) {                         // lanes 0 and 32 cover both hi sets
    #pragma unroll
    for (int reg = 0; reg < 16; ++reg)
      stab[w][(reg & 3) + 8*(reg >> 2) + 4*hi] = ones_acc[reg];
  }
  __syncthreads();

  float* Ocomb = (float*)&Ks[0][0];       // [4][32 q][64 d] f32 = 32 KB
  const int wA = w & ~1, wB = w | 1;
  if (sub == 1) {
    #pragma unroll
    for (int reg = 0; reg < 16; ++reg) {
      const int cr = (reg & 3) + 8*(reg >> 2) + 4*hi;
      float mA = mtab[wA][cr], mB = mtab[wB][cr];
      float fB = exp2_fast(mB - fmaxf(mA, mB));
      Ocomb[(j*32 + cr)*64 +      l31] = yacc0[reg] * fB;
      Ocomb[(j*32 + cr)*64 + 32 + l31] = yacc1[reg] * fB;
    }
  }
  __syncthreads();
  if (sub == 0) {
    #pragma unroll
    for (int reg = 0; reg < 16; ++reg) {
      const int cr = (reg & 3) + 8*(reg >> 2) + 4*hi;
      float mA = mtab[wA][cr], mB = mtab[wB][cr];
      float sA = stab[wA][cr], sB = stab[wB][cr];
      float ms = fmaxf(mA, mB);
      float fA = exp2_fast(mA - ms), fB = exp2_fast(mB - ms);
      float inv = 1.f / (sA * fA + sB * fB);
      const size_t orow = ((size_t)bidx*SEQ + qt*128 + j*32 + cr)*CH + h*HDIM;
      float v0 = (yacc0[reg] * fA + Ocomb[(j*32 + cr)*64 +      l31]) * inv;
      float v1 = (yacc1[reg] * fA + Ocomb[(j*32 + cr)*64 + 32 + l31]) * inv;
      yout[orow +      l31] = f2b(v0);
      yout[orow + 32 + l31] = f2b(v1);
    }
  }
#undef ATTN_STAGE
#undef PACK
}

extern "C" void kernel_launch(void* const* d_in, const int* in_sizes, int n_in,
                              void* d_out, int out_size, void* d_ws, size_t ws_size,
                              hipStream_t stream) {
  (void)in_sizes; (void)n_in; (void)out_size; (void)ws_size;
  const float* x      = (const float*)d_in[0];
  const float* w_attn = (const float*)d_in[1];
  const float* b_attn = (const float*)d_in[2];
  const float* w_proj = (const float*)d_in[3];
  const float* b_proj = (const float*)d_in[4];

  char* ws = (char*)d_ws;
  const size_t MB = 1024*1024;
  u16* xb  = (u16*)(ws);             // 8 MB, reused as attention out y
  u16* wat = (u16*)(ws +  8*MB);     // 6 MB  w_attn^T [3072][1024]
  u16* wpt = (u16*)(ws + 14*MB);     // 2 MB  w_proj^T [1024][1024]
  u16* qb  = (u16*)(ws + 16*MB);     // 8 MB  [bh][t][64]
  u16* kb  = (u16*)(ws + 24*MB);     // 8 MB  [bh][t][64]
  u16* vtb = (u16*)(ws + 32*MB);     // 8 MB  [bh][64][t]

  csa_prep<<<6144, 256, 0, stream>>>(x, w_attn, w_proj, xb, wat, wpt);
  csa_gemm_qkv<<<dim3(16, 16), 512, 0, stream>>>(xb, wat, b_attn, qb, kb, vtb);
  csa_attn<<<dim3(32, 16), 512, 0, stream>>>(qb, kb, vtb, xb);
  csa_gemm_proj<<<dim3(8, 32), 256, 0, stream>>>(xb, wpt, b_proj, (float*)d_out);
}